// Round 20
// baseline (466.339 us; speedup 1.0000x reference)
//
#include <hip/hip_runtime.h>
#include <stdint.h>

// MoERankingModel: B=131072, D_IN=512, H=256, E=8, TOPK=2, TASKS=1
// R20 = R19 + __launch_bounds__(512, 4) on k_hg (request 2 workgroups/CU via
// occupancy metadata; VGPR cap 128 >= current 104, so no R5-style clamp).
// Tests whether the 1-block/CU pin (occ 22.5% across LDS 100/67.6/65.5KB)
// is compiler-metadata-driven.
// Ledger: R15/R18 413.7-413.9us (best); R19 (64KiB LDS + swizzle) 415.7.
// k_hg floor 218-224 over 9 variants; expert M={32:340, 64:196, 128:224}.

#define NB 131072
#define DIN 512
#define HD 256

typedef short s16x8 __attribute__((ext_vector_type(8)));
typedef float f32x4 __attribute__((ext_vector_type(4)));

__device__ __forceinline__ unsigned short f2bf(float f) {
  uint32_t u = __builtin_bit_cast(uint32_t, f);
  u += 0x7FFFu + ((u >> 16) & 1u);   // RNE
  return (unsigned short)(u >> 16);
}
__device__ __forceinline__ float bf2f(unsigned short s) {
  uint32_t u = ((uint32_t)s) << 16;
  return __builtin_bit_cast(float, u);
}

// ---------------- prep: transposed bf16 weights ----------------
__global__ void k_prep_t(const float* __restrict__ Win, const float* __restrict__ W1,
                         const float* __restrict__ W2, const float* __restrict__ Wh1,
                         unsigned short* wt_in, unsigned short* w1t,
                         unsigned short* w2t, unsigned short* wh1t) {
  const int total = 131072 + 524288 + 524288 + 32768;
  for (int idx = blockIdx.x * 256 + threadIdx.x; idx < total; idx += gridDim.x * 256) {
    if (idx < 131072) {
      int n = idx >> 9, d = idx & 511;
      wt_in[idx] = f2bf(Win[d * 256 + n]);
    } else if (idx < 655360) {
      int i = idx - 131072;
      int e = i >> 16, n = (i >> 8) & 255, k = i & 255;
      w1t[i] = f2bf(W1[(e * 256 + k) * 256 + n]);
    } else if (idx < 1179648) {
      int i = idx - 655360;
      int e = i >> 16, n = (i >> 8) & 255, k = i & 255;
      w2t[i] = f2bf(W2[(e * 256 + k) * 256 + n]);
    } else {
      int i = idx - 1179648;              // i = j*256 + h, j<128
      int j = i >> 8, h = i & 255;
      wh1t[i] = f2bf(Wh1[h * 128 + j]);
    }
  }
}

// wf[d][e] = sum_h W_in[d][h]*Wg[h][e] (f64);  bfv[e] = b_in@Wg + bg
__global__ void k_prep_gate(const float* __restrict__ Win, const float* __restrict__ Wg,
                            const float* __restrict__ b_in, const float* __restrict__ bg,
                            double* wf, double* bfv) {
  int t = blockIdx.x * 256 + threadIdx.x;
  if (t < 4096) {
    int d = t >> 3, e = t & 7;
    double acc = 0.0;
    for (int h = 0; h < 256; ++h)
      acc += (double)Win[d * 256 + h] * (double)Wg[h * 8 + e];
    wf[t] = acc;
  }
  if (blockIdx.x == 0 && threadIdx.x < 8) {
    int e = threadIdx.x;
    double acc = (double)bg[e];
    for (int h = 0; h < 256; ++h) acc += (double)b_in[h] * (double)Wg[h * 8 + e];
    bfv[e] = acc;
  }
}

// ------------- FUSED: h = x@W_in + b_in (bf16 MFMA) + f64 gate top-2 -------------
// R15 ILP staging; xt[128*256] XOR-swizzled (65536 B exactly); wfld aliased
// onto xt after the last MFMA barrier; gate numerics identical to R15.
// (512,4): advertise 4 waves/EU so 2 workgroups/CU can co-schedule.
__global__ __launch_bounds__(512, 4) void k_hg(const float* __restrict__ x,
                                               const unsigned short* __restrict__ wt_in,
                                               const float* __restrict__ b_in,
                                               const double* __restrict__ wf,
                                               const double* __restrict__ bfv,
                                               unsigned short* __restrict__ hbuf,
                                               float2* __restrict__ g12,
                                               unsigned int* __restrict__ eidx) {
  __shared__ unsigned short xt[128 * 256];   // 65536 B exactly; swizzled
  const int tid = threadIdx.x;
  const int lane = tid & 63, wid = tid >> 6;
  const int wr = wid >> 2, wc = wid & 3;
  const int row0 = blockIdx.x * 128;

  f32x4 acc[4][4];
#pragma unroll
  for (int mi = 0; mi < 4; ++mi)
#pragma unroll
    for (int ni = 0; ni < 4; ++ni) acc[mi][ni] = (f32x4)0.0f;

  const int arow = wr * 64 + (lane & 15);
  const int bcol0 = wc * 64 + (lane & 15);
  const int koff = (lane >> 4) * 8;
  const int aswz = (lane & 7) << 3;          // (arow&7)<<3, constant per thread

  // ---- batched staging: ks=0 loads (16 in flight) ----
  f32x4 va[8], vb[8];
#pragma unroll
  for (int i = 0; i < 8; ++i) {
    int flat = tid + i * 512;
    int r = flat >> 5, c8 = flat & 31;
    const float* src = x + (size_t)(row0 + r) * 512 + c8 * 8;
    va[i] = *(const f32x4*)src;
    vb[i] = *(const f32x4*)(src + 4);
  }
#pragma unroll
  for (int i = 0; i < 8; ++i) {
    int flat = tid + i * 512;
    int r = flat >> 5, c8 = flat & 31;
    s16x8 sv;
    sv[0] = (short)f2bf(va[i][0]); sv[1] = (short)f2bf(va[i][1]);
    sv[2] = (short)f2bf(va[i][2]); sv[3] = (short)f2bf(va[i][3]);
    sv[4] = (short)f2bf(vb[i][0]); sv[5] = (short)f2bf(vb[i][1]);
    sv[6] = (short)f2bf(vb[i][2]); sv[7] = (short)f2bf(vb[i][3]);
    *(s16x8*)&xt[(r * 256 + c8 * 8) ^ ((r & 7) << 3)] = sv;
  }
  __syncthreads();

  // ---- issue ks=1 loads now; they fly under ks=0 MFMA ----
#pragma unroll
  for (int i = 0; i < 8; ++i) {
    int flat = tid + i * 512;
    int r = flat >> 5, c8 = flat & 31;
    const float* src = x + (size_t)(row0 + r) * 512 + 256 + c8 * 8;
    va[i] = *(const f32x4*)src;
    vb[i] = *(const f32x4*)(src + 4);
  }

  // ---- MFMA over ks=0 ----
#pragma unroll
  for (int kk = 0; kk < 8; ++kk) {
    int k0 = kk * 32 + koff;
    s16x8 af[4], bfr[4];
#pragma unroll
    for (int mi = 0; mi < 4; ++mi)
      af[mi] = *(const s16x8*)&xt[(((arow + mi * 16) * 256 + k0)) ^ aswz];
#pragma unroll
    for (int ni = 0; ni < 4; ++ni)
      bfr[ni] = *(const s16x8*)(wt_in + (size_t)(bcol0 + ni * 16) * 512 + k0);
#pragma unroll
    for (int mi = 0; mi < 4; ++mi)
#pragma unroll
      for (int ni = 0; ni < 4; ++ni)
        acc[mi][ni] = __builtin_amdgcn_mfma_f32_16x16x32_bf16(af[mi], bfr[ni], acc[mi][ni], 0, 0, 0);
  }
  __syncthreads();   // everyone done reading xt(ks=0)

  // ---- store ks=1 tile ----
#pragma unroll
  for (int i = 0; i < 8; ++i) {
    int flat = tid + i * 512;
    int r = flat >> 5, c8 = flat & 31;
    s16x8 sv;
    sv[0] = (short)f2bf(va[i][0]); sv[1] = (short)f2bf(va[i][1]);
    sv[2] = (short)f2bf(va[i][2]); sv[3] = (short)f2bf(va[i][3]);
    sv[4] = (short)f2bf(vb[i][0]); sv[5] = (short)f2bf(vb[i][1]);
    sv[6] = (short)f2bf(vb[i][2]); sv[7] = (short)f2bf(vb[i][3]);
    *(s16x8*)&xt[(r * 256 + c8 * 8) ^ ((r & 7) << 3)] = sv;
  }
  __syncthreads();

  // ---- MFMA over ks=1 ----
#pragma unroll
  for (int kk = 0; kk < 8; ++kk) {
    int k0 = kk * 32 + koff;
    s16x8 af[4], bfr[4];
#pragma unroll
    for (int mi = 0; mi < 4; ++mi)
      af[mi] = *(const s16x8*)&xt[(((arow + mi * 16) * 256 + k0)) ^ aswz];
#pragma unroll
    for (int ni = 0; ni < 4; ++ni)
      bfr[ni] = *(const s16x8*)(wt_in + (size_t)(bcol0 + ni * 16) * 512 + 256 + k0);
#pragma unroll
    for (int mi = 0; mi < 4; ++mi)
#pragma unroll
      for (int ni = 0; ni < 4; ++ni)
        acc[mi][ni] = __builtin_amdgcn_mfma_f32_16x16x32_bf16(af[mi], bfr[ni], acc[mi][ni], 0, 0, 0);
  }
  __syncthreads();   // all xt(ks=1) reads done -> safe to overwrite with wfld

  // ---- load wfld into the SAME LDS space ([4][1026] padded, 32.8 KB) ----
  double* wfld = (double*)xt;
  for (int i = tid; i < 4096; i += 512)
    wfld[(i >> 10) * 1026 + (i & 1023)] = wf[i];

  // ---- h epilogue (global stores; overlaps wfld loads) ----
  const int r4 = (lane >> 4) * 4;
#pragma unroll
  for (int ni = 0; ni < 4; ++ni) {
    int col = wc * 64 + ni * 16 + (lane & 15);
    float bin = b_in[col];
#pragma unroll
    for (int mi = 0; mi < 4; ++mi) {
      int rbase = row0 + wr * 64 + mi * 16 + r4;
#pragma unroll
      for (int j = 0; j < 4; ++j)
        hbuf[(size_t)(rbase + j) * 256 + col] = f2bf(acc[mi][ni][j] + bin);
    }
  }
  __syncthreads();   // wfld visible

  // ---- gate: 4 threads/token, d-quarter each, f64 (R15 exact) ----
  const int r = tid >> 2, q = tid & 3;
  double z[8];
#pragma unroll
  for (int e = 0; e < 8; ++e) z[e] = 0.0;
  const float* xrow = x + (size_t)(row0 + r) * 512 + q * 128;
  const double* wq = &wfld[q * 1026];
  for (int dd = 0; dd < 32; ++dd) {
    f32x4 xv = *(const f32x4*)(xrow + dd * 4);
#pragma unroll
    for (int j = 0; j < 4; ++j) {
      double xd = (double)xv[j];
      const double* wrow = wq + (dd * 4 + j) * 8;
#pragma unroll
      for (int e = 0; e < 8; ++e) z[e] += xd * wrow[e];
    }
  }
#pragma unroll
  for (int e = 0; e < 8; ++e) {
    z[e] += __shfl_xor(z[e], 1);
    z[e] += __shfl_xor(z[e], 2);
  }
  if (q == 0) {
#pragma unroll
    for (int e = 0; e < 8; ++e) z[e] += bfv[e];
    int i1 = 0; double m1 = z[0];
#pragma unroll
    for (int e = 1; e < 8; ++e) if (z[e] > m1) { m1 = z[e]; i1 = e; }
    int i2 = -1; double m2 = -1e300;
#pragma unroll
    for (int e = 0; e < 8; ++e) if (e != i1 && z[e] > m2) { m2 = z[e]; i2 = e; }
    double s = exp(m2 - m1);
    int token = row0 + r;
    g12[token] = make_float2((float)(1.0 / (1.0 + s)), (float)(s / (1.0 + s)));
    eidx[token] = (unsigned)(i1 | (i2 << 4));
  }
}

// ---------------- hist: per-block (256 tokens) expert histogram ----------------
__global__ __launch_bounds__(256) void k_hist(const unsigned int* __restrict__ eidx,
                                              unsigned int* __restrict__ bhist) {
  __shared__ unsigned int wcnt[4][8];
  const int tid = threadIdx.x;
  const int w = tid >> 6, lane = tid & 63;
  unsigned v = eidx[blockIdx.x * 256 + tid];
  int i1 = (int)(v & 15u), i2 = (int)((v >> 4) & 15u);
#pragma unroll
  for (int e = 0; e < 8; ++e) {
    unsigned long long m0 = __ballot(i1 == e);
    unsigned long long m1 = __ballot(i2 == e);
    if (lane == 0) wcnt[w][e] = (unsigned)(__popcll(m0) + __popcll(m1));
  }
  __syncthreads();
  if (tid < 8)
    bhist[blockIdx.x * 8 + tid] =
        wcnt[0][tid] + wcnt[1][tid] + wcnt[2][tid] + wcnt[3][tid];
}

// scan: wave e scans expert e's 512 block counts -> exclusive bases + meta
// meta[e]=64-row tile base, meta[8]=total tiles, meta[16+e]=count, meta[32+e]=row base
__global__ __launch_bounds__(512) void k_scan1(const unsigned int* __restrict__ bhist,
                                               unsigned int* __restrict__ bbase,
                                               unsigned int* __restrict__ meta) {
  __shared__ unsigned int tot[8];
  const int tid = threadIdx.x;
  const int e = tid >> 6, lane = tid & 63;
  unsigned run = 0;
  for (int c = 0; c < 8; ++c) {           // 8 chunks x 64 lanes = 512 blocks
    int b = c * 64 + lane;
    unsigned v = bhist[b * 8 + e];
    unsigned s = v;
#pragma unroll
    for (int d = 1; d < 64; d <<= 1) {
      unsigned t2 = __shfl_up(s, d);
      if (lane >= d) s += t2;
    }
    bbase[b * 8 + e] = run + s - v;       // exclusive within expert
    run += (unsigned)__shfl(s, 63);
  }
  if (lane == 63) tot[e] = run;
  __syncthreads();
  if (tid == 0) {
    unsigned bb = 0;
    for (int i = 0; i < 8; ++i) {
      meta[i] = bb;                 // 64-row tile base
      meta[16 + i] = tot[i];
      meta[32 + i] = bb * 64u;      // row base
      bb += (tot[i] + 63u) >> 6;
    }
    meta[8] = bb;
  }
}

// scatter: position = rowBase[e] + blockBase + waveBase + ballot rank. No atomics.
__global__ __launch_bounds__(256) void k_scatter2(const unsigned int* __restrict__ eidx,
                                                  const unsigned int* __restrict__ bbase,
                                                  const unsigned int* __restrict__ meta,
                                                  unsigned int* __restrict__ perm) {
  __shared__ unsigned int wcnt[4][8];
  const int tid = threadIdx.x;
  const int w = tid >> 6, lane = tid & 63;
  const int t = blockIdx.x * 256 + tid;
  unsigned v = eidx[t];
  int i1 = (int)(v & 15u), i2 = (int)((v >> 4) & 15u);
  unsigned long long m0[8], m1[8];
#pragma unroll
  for (int e = 0; e < 8; ++e) {
    m0[e] = __ballot(i1 == e);
    m1[e] = __ballot(i2 == e);
    if (lane == 0) wcnt[w][e] = (unsigned)(__popcll(m0[e]) + __popcll(m1[e]));
  }
  __syncthreads();
  const unsigned long long below = (1ull << lane) - 1ull;
#pragma unroll
  for (int e = 0; e < 8; ++e) {
    unsigned base = meta[32 + e] + bbase[blockIdx.x * 8 + e];
    for (int w2 = 0; w2 < w; ++w2) base += wcnt[w2][e];
    if (i1 == e) {
      unsigned r = (unsigned)__popcll(m0[e] & below);
      perm[base + r] = (unsigned)(t * 2);
    }
    if (i2 == e) {
      unsigned r = (unsigned)__popcll(m0[e]) + (unsigned)__popcll(m1[e] & below);
      perm[base + r] = (unsigned)(t * 2 + 1);
    }
  }
}

// ------------- grouped expert FFN (R6 config: M=64, single 34KB LDS) -------------
// e1=relu(h@W1+b1); eo=e1@W2+b2; proj=eo@Wh1
__global__ __launch_bounds__(512) void k_expert(const unsigned short* __restrict__ hbuf,
                                                const unsigned short* __restrict__ w1t,
                                                const unsigned short* __restrict__ w2t,
                                                const unsigned short* __restrict__ wh1t,
                                                const float* __restrict__ b1,
                                                const float* __restrict__ b2,
                                                const unsigned int* __restrict__ meta,
                                                const unsigned int* __restrict__ perm,
                                                unsigned short* __restrict__ proj) {
  __shared__ unsigned short xt[64 * 264];    // h -> e1 -> eo (single buffer)
  __shared__ int ptok[64];
  const int b = blockIdx.x;
  if (b >= (int)meta[8]) return;
  int e = 0;
  while (e < 7 && (int)meta[e + 1] <= b) ++e;
  const int limit = (int)(meta[e] * 64u + meta[16 + e]);  // first invalid row
  const int row0 = b * 64;
  const int tid = threadIdx.x;
  if (tid < 64) {
    int r = row0 + tid;
    ptok[tid] = (r < limit) ? (int)perm[r] : -1;
  }
  __syncthreads();
#pragma unroll
  for (int i = 0; i < 4; ++i) {
    int flat = tid + i * 512;
    int r = flat >> 5, c8 = flat & 31;
    int pt = ptok[r];
    s16x8 v = (s16x8)(short)0;
    if (pt >= 0) {
      int token = pt >> 1;
      v = *(const s16x8*)(hbuf + (size_t)token * 256 + c8 * 8);
    }
    *(s16x8*)&xt[r * 264 + c8 * 8] = v;
  }
  __syncthreads();

  const int lane = tid & 63, wid = tid >> 6;  // 8 waves: 64 rows x 32 cols each
  const int arow = lane & 15;
  const int koff = (lane >> 4) * 8;
  const int r4 = (lane >> 4) * 4;
  const int colb = wid * 32 + (lane & 15);

  f32x4 acc[4][2];
  // ---- G1: acc = h @ W1 ----
#pragma unroll
  for (int mi = 0; mi < 4; ++mi) { acc[mi][0] = (f32x4)0.0f; acc[mi][1] = (f32x4)0.0f; }
  const unsigned short* w1e = w1t + (size_t)e * 65536;
#pragma unroll
  for (int kk = 0; kk < 8; ++kk) {
    int k0 = kk * 32 + koff;
    s16x8 af[4], bfr[2];
#pragma unroll
    for (int mi = 0; mi < 4; ++mi)
      af[mi] = *(const s16x8*)&xt[(arow + mi * 16) * 264 + k0];
#pragma unroll
    for (int ni = 0; ni < 2; ++ni)
      bfr[ni] = *(const s16x8*)(w1e + (size_t)(colb + ni * 16) * 256 + k0);
#pragma unroll
    for (int mi = 0; mi < 4; ++mi)
#pragma unroll
      for (int ni = 0; ni < 2; ++ni)
        acc[mi][ni] = __builtin_amdgcn_mfma_f32_16x16x32_bf16(af[mi], bfr[ni], acc[mi][ni], 0, 0, 0);
  }
  __syncthreads();   // all waves done reading h from xt
#pragma unroll
  for (int ni = 0; ni < 2; ++ni) {
    int col = colb + ni * 16;
    float bb1 = b1[e * 256 + col];
#pragma unroll
    for (int mi = 0; mi < 4; ++mi) {
      int rl = mi * 16 + r4;
#pragma unroll
      for (int j = 0; j < 4; ++j) {
        float v = acc[mi][ni][j] + bb1;
        v = v > 0.f ? v : 0.f;
        xt[(rl + j) * 264 + col] = f2bf(v);      // e1 overwrites h
      }
    }
  }
  __syncthreads();

  // ---- G2: acc = e1 @ W2 ----
#pragma unroll
  for (int mi = 0; mi < 4; ++mi) { acc[mi][0] = (f32x4)0.0f; acc[mi][1] = (f32x4)0.0f; }
  const unsigned short* w2e = w2t + (size_t)e * 65536;
#pragma unroll
  for (int kk = 0; kk < 8; ++kk) {
    int k0 = kk * 32 + koff;
    s16x8 af[4], bfr[2];
#pragma unroll
    for (int mi = 0; mi < 4; ++mi)
      af[mi] = *(const s16x8*)&xt[(arow + mi * 16) * 264 + k0];
#pragma unroll
    for (int ni = 0; ni < 2; ++ni)
      bfr[ni] = *(const s16x8*)(w2e + (size_t)(colb + ni * 16) * 256 + k0);
#pragma unroll
    for (int mi = 0; mi < 4; ++mi)
#pragma unroll
      for (int ni = 0; ni < 2; ++ni)
        acc[mi][ni] = __builtin_amdgcn_mfma_f32_16x16x32_bf16(af[mi], bfr[ni], acc[mi][ni], 0, 0, 0);
  }
  __syncthreads();   // all waves done reading e1 from xt
#pragma unroll
  for (int ni = 0; ni < 2; ++ni) {
    int col = colb + ni * 16;
    float bb2 = b2[e * 256 + col];
#pragma unroll
    for (int mi = 0; mi < 4; ++mi) {
      int rl = mi * 16 + r4;
#pragma unroll
      for (int j = 0; j < 4; ++j)
        xt[(rl + j) * 264 + col] = f2bf(acc[mi][ni][j] + bb2);   // eo overwrites e1
    }
  }
  __syncthreads();

  // ---- G3: proj = eo @ Wh1  (output 64 x 128; 8 waves x 16 cols) ----
  f32x4 acc3[4];
#pragma unroll
  for (int mi = 0; mi < 4; ++mi) acc3[mi] = (f32x4)0.0f;
  const int col3 = wid * 16 + (lane & 15);
#pragma unroll
  for (int kk = 0; kk < 8; ++kk) {
    int k0 = kk * 32 + koff;
    s16x8 af[4];
#pragma unroll
    for (int mi = 0; mi < 4; ++mi)
      af[mi] = *(const s16x8*)&xt[(arow + mi * 16) * 264 + k0];
    s16x8 bfr = *(const s16x8*)(wh1t + (size_t)col3 * 256 + k0);
#pragma unroll
    for (int mi = 0; mi < 4; ++mi)
      acc3[mi] = __builtin_amdgcn_mfma_f32_16x16x32_bf16(af[mi], bfr, acc3[mi], 0, 0, 0);
  }
#pragma unroll
  for (int mi = 0; mi < 4; ++mi) {
#pragma unroll
    for (int j = 0; j < 4; ++j) {
      int rl = mi * 16 + r4 + j;
      int pt = ptok[rl];
      if (pt >= 0)
        proj[(size_t)pt * 128 + col3] = f2bf(acc3[mi][j]);
    }
  }
}

// ------------- combine + head: y=relu(g1*p1+g2*p2+bh1); out=y@Wh2+bh2 -------------
__global__ __launch_bounds__(256) void k_head(const unsigned short* __restrict__ proj,
                                              const float2* __restrict__ g12,
                                              const float* __restrict__ bh1,
                                              const float* __restrict__ wh2,
                                              const float* __restrict__ bh2,
                                              float* __restrict__ out) {
  __shared__ float sbh1[128];
  __shared__ float swh2[128];
  const int tid = threadIdx.x;
  if (tid < 128) { sbh1[tid] = bh1[tid]; swh2[tid] = wh2[tid]; }
  __syncthreads();
  const int token = blockIdx.x * 128 + (tid >> 1);
  const int half = tid & 1;
  const int j0 = half * 64;
  float2 g = g12[token];
  const unsigned short* p1 = proj + (size_t)token * 256 + j0;        // slot 0 row
  const unsigned short* p2 = p1 + 128;                               // slot 1 row
  float sum = 0.f;
#pragma unroll
  for (int c = 0; c < 8; ++c) {
    s16x8 a = *(const s16x8*)(p1 + c * 8);
    s16x8 b = *(const s16x8*)(p2 + c * 8);
#pragma unroll
    for (int jj = 0; jj < 8; ++jj) {
      int j = j0 + c * 8 + jj;
      float v = g.x * bf2f((unsigned short)a[jj]) + g.y * bf2f((unsigned short)b[jj]) + sbh1[j];
      v = fmaxf(v, 0.f);
      sum += v * swh2[j];
    }
  }
  sum += __shfl_xor(sum, 1);
  if (half == 0) out[token] = sum + bh2[0];
}

extern "C" void kernel_launch(void* const* d_in, const int* in_sizes, int n_in,
                              void* d_out, int out_size, void* d_ws, size_t ws_size,
                              hipStream_t stream) {
  const float* x   = (const float*)d_in[0];
  const float* Win = (const float*)d_in[1];
  const float* bin = (const float*)d_in[2];
  const float* W1  = (const float*)d_in[3];
  const float* b1  = (const float*)d_in[4];
  const float* W2  = (const float*)d_in[5];
  const float* b2  = (const float*)d_in[6];
  const float* Wg  = (const float*)d_in[7];
  const float* bg  = (const float*)d_in[8];
  const float* Wh1 = (const float*)d_in[9];
  const float* bh1 = (const float*)d_in[10];
  const float* Wh2 = (const float*)d_in[11];
  const float* bh2 = (const float*)d_in[12];

  char* ws = (char*)d_ws;
  size_t o = 0;
  auto alloc = [&](size_t n) { o = (o + 255) & ~(size_t)255; void* p = ws + o; o += n; return p; };
  unsigned short* wt_in = (unsigned short*)alloc(262144);
  unsigned short* w1t   = (unsigned short*)alloc(1048576);
  unsigned short* w2t   = (unsigned short*)alloc(1048576);
  unsigned short* wh1t  = (unsigned short*)alloc(65536);
  double*        wf     = (double*)alloc(32768);
  double*        bfv    = (double*)alloc(64);
  unsigned short* hbuf  = (unsigned short*)alloc((size_t)NB * 256 * 2);        // 67.1 MB
  float2*        g12    = (float2*)alloc((size_t)NB * 8);
  unsigned int*  eidx   = (unsigned int*)alloc((size_t)NB * 4);
  unsigned int*  bhist  = (unsigned int*)alloc(512 * 8 * 4);
  unsigned int*  bbase  = (unsigned int*)alloc(512 * 8 * 4);
  unsigned int*  meta   = (unsigned int*)alloc(256);
  unsigned int*  perm   = (unsigned int*)alloc(((size_t)NB * 2 + 2048) * 4);   // padded
  unsigned short* proj  = (unsigned short*)alloc((size_t)NB * 2 * 128 * 2);    // 67.1 MB
  (void)ws_size; (void)in_sizes; (void)n_in; (void)out_size;  // ~139.4 MB used

  k_prep_t<<<2048, 256, 0, stream>>>(Win, W1, W2, Wh1, wt_in, w1t, w2t, wh1t);
  k_prep_gate<<<16, 256, 0, stream>>>(Win, Wg, bin, bg, wf, bfv);
  k_hg<<<NB / 128, 512, 0, stream>>>(x, wt_in, bin, wf, bfv, hbuf, g12, eidx);
  k_hist<<<NB / 256, 256, 0, stream>>>(eidx, bhist);
  k_scan1<<<1, 512, 0, stream>>>(bhist, bbase, meta);
  k_scatter2<<<NB / 256, 256, 0, stream>>>(eidx, bbase, meta, perm);
  k_expert<<<NB * 2 / 64 + 8, 512, 0, stream>>>(hbuf, w1t, w2t, wh1t, b1, b2, meta, perm, proj);
  k_head<<<NB / 128, 256, 0, stream>>>(proj, g12, bh1, (const float*)Wh2, bh2, (float*)d_out);
}

// Round 21
// 404.527 us; speedup vs baseline: 1.1528x; 1.1528x over previous
//
#include <hip/hip_runtime.h>
#include <stdint.h>

// MoERankingModel: B=131072, D_IN=512, H=256, E=8, TOPK=2, TASKS=1
// R21 = (512,4) occupancy metadata (PROVEN to give 2 blocks/CU in R20) +
// k_hg rebuilt to fit the 64-VGPR cap: M=64 tile, 8 waves x (64x32),
// acc[4][2]=32 regs (R12/R13 GEMM shape, measured VGPR 48-52), simple
// staging, R15-style LDS-wfld gate at 8 threads/token. LDS 66.6KB <= 80KB.
// Ledger: R15/R18 413.7 best. R20: (512,4) -> occ 42.8% but VGPR clamp 64
// spilled the acc[4][4]+va/vb kernel (WRITE 107->235MB). Expert M=64 fixed.

#define NB 131072
#define DIN 512
#define HD 256

typedef short s16x8 __attribute__((ext_vector_type(8)));
typedef float f32x4 __attribute__((ext_vector_type(4)));

__device__ __forceinline__ unsigned short f2bf(float f) {
  uint32_t u = __builtin_bit_cast(uint32_t, f);
  u += 0x7FFFu + ((u >> 16) & 1u);   // RNE
  return (unsigned short)(u >> 16);
}
__device__ __forceinline__ float bf2f(unsigned short s) {
  uint32_t u = ((uint32_t)s) << 16;
  return __builtin_bit_cast(float, u);
}

// ---------------- prep: transposed bf16 weights ----------------
__global__ void k_prep_t(const float* __restrict__ Win, const float* __restrict__ W1,
                         const float* __restrict__ W2, const float* __restrict__ Wh1,
                         unsigned short* wt_in, unsigned short* w1t,
                         unsigned short* w2t, unsigned short* wh1t) {
  const int total = 131072 + 524288 + 524288 + 32768;
  for (int idx = blockIdx.x * 256 + threadIdx.x; idx < total; idx += gridDim.x * 256) {
    if (idx < 131072) {
      int n = idx >> 9, d = idx & 511;
      wt_in[idx] = f2bf(Win[d * 256 + n]);
    } else if (idx < 655360) {
      int i = idx - 131072;
      int e = i >> 16, n = (i >> 8) & 255, k = i & 255;
      w1t[i] = f2bf(W1[(e * 256 + k) * 256 + n]);
    } else if (idx < 1179648) {
      int i = idx - 655360;
      int e = i >> 16, n = (i >> 8) & 255, k = i & 255;
      w2t[i] = f2bf(W2[(e * 256 + k) * 256 + n]);
    } else {
      int i = idx - 1179648;              // i = j*256 + h, j<128
      int j = i >> 8, h = i & 255;
      wh1t[i] = f2bf(Wh1[h * 128 + j]);
    }
  }
}

// wf[d][e] = sum_h W_in[d][h]*Wg[h][e] (f64);  bfv[e] = b_in@Wg + bg
__global__ void k_prep_gate(const float* __restrict__ Win, const float* __restrict__ Wg,
                            const float* __restrict__ b_in, const float* __restrict__ bg,
                            double* wf, double* bfv) {
  int t = blockIdx.x * 256 + threadIdx.x;
  if (t < 4096) {
    int d = t >> 3, e = t & 7;
    double acc = 0.0;
    for (int h = 0; h < 256; ++h)
      acc += (double)Win[d * 256 + h] * (double)Wg[h * 8 + e];
    wf[t] = acc;
  }
  if (blockIdx.x == 0 && threadIdx.x < 8) {
    int e = threadIdx.x;
    double acc = (double)bg[e];
    for (int h = 0; h < 256; ++h) acc += (double)b_in[h] * (double)Wg[h * 8 + e];
    bfv[e] = acc;
  }
}

// ------------- FUSED: h = x@W_in + b_in (bf16 MFMA, M=64) + f64 gate top-2 -------------
// (512,4): 2 workgroups/CU. acc[4][2] keeps VGPR under the 64 cap.
// Gate: 8 threads/token, 64 d each, wfld in padded LDS ([4][1026]).
__global__ __launch_bounds__(512, 4) void k_hg(const float* __restrict__ x,
                                               const unsigned short* __restrict__ wt_in,
                                               const float* __restrict__ b_in,
                                               const double* __restrict__ wf,
                                               const double* __restrict__ bfv,
                                               unsigned short* __restrict__ hbuf,
                                               float2* __restrict__ g12,
                                               unsigned int* __restrict__ eidx) {
  __shared__ unsigned short xt[64 * 264];    // 33.8 KB
  __shared__ double wfld[4 * 1026];          // 32.8 KB  (total 66.6 KB)
  const int tid = threadIdx.x;
  const int lane = tid & 63, wid = tid >> 6;
  const int row0 = blockIdx.x * 64;

  for (int i = tid; i < 4096; i += 512)
    wfld[(i >> 10) * 1026 + (i & 1023)] = wf[i];

  // ---- GEMM: 8 waves x (64 rows x 32 cols) ----
  const int arow = lane & 15;
  const int colb = wid * 32 + (lane & 15);
  const int koff = (lane >> 4) * 8;
  const int r4 = (lane >> 4) * 4;
  f32x4 acc[4][2];
#pragma unroll
  for (int mi = 0; mi < 4; ++mi) { acc[mi][0] = (f32x4)0.0f; acc[mi][1] = (f32x4)0.0f; }

  for (int ks = 0; ks < 2; ++ks) {
    __syncthreads();                        // also publishes wfld (first iter)
#pragma unroll
    for (int i = 0; i < 4; ++i) {
      int flat = tid + i * 512;
      int r = flat >> 5, c8 = flat & 31;
      const float* src = x + (size_t)(row0 + r) * 512 + ks * 256 + c8 * 8;
      f32x4 v0 = *(const f32x4*)src;
      f32x4 v1 = *(const f32x4*)(src + 4);
      s16x8 sv;
      sv[0] = (short)f2bf(v0[0]); sv[1] = (short)f2bf(v0[1]);
      sv[2] = (short)f2bf(v0[2]); sv[3] = (short)f2bf(v0[3]);
      sv[4] = (short)f2bf(v1[0]); sv[5] = (short)f2bf(v1[1]);
      sv[6] = (short)f2bf(v1[2]); sv[7] = (short)f2bf(v1[3]);
      *(s16x8*)&xt[r * 264 + c8 * 8] = sv;
    }
    __syncthreads();
#pragma unroll
    for (int kk = 0; kk < 8; ++kk) {
      int k0 = kk * 32 + koff;
      s16x8 af[4], bfr[2];
#pragma unroll
      for (int mi = 0; mi < 4; ++mi)
        af[mi] = *(const s16x8*)&xt[(arow + mi * 16) * 264 + k0];
#pragma unroll
      for (int ni = 0; ni < 2; ++ni)
        bfr[ni] = *(const s16x8*)(wt_in + (size_t)(colb + ni * 16) * 512 + ks * 256 + k0);
#pragma unroll
      for (int mi = 0; mi < 4; ++mi)
#pragma unroll
        for (int ni = 0; ni < 2; ++ni)
          acc[mi][ni] = __builtin_amdgcn_mfma_f32_16x16x32_bf16(af[mi], bfr[ni], acc[mi][ni], 0, 0, 0);
    }
  }
#pragma unroll
  for (int ni = 0; ni < 2; ++ni) {
    int col = colb + ni * 16;
    float bin = b_in[col];
#pragma unroll
    for (int mi = 0; mi < 4; ++mi) {
      int rbase = row0 + mi * 16 + r4;
#pragma unroll
      for (int j = 0; j < 4; ++j)
        hbuf[(size_t)(rbase + j) * 256 + col] = f2bf(acc[mi][ni][j] + bin);
    }
  }

  // ---- gate: 8 threads/token (d-slice of 64 each), f64, wfld in LDS ----
  const int tok = tid >> 3, s8 = tid & 7;   // token 0..63, slice 0..7
  double z[8];
#pragma unroll
  for (int e = 0; e < 8; ++e) z[e] = 0.0;
  const float* xrow = x + (size_t)(row0 + tok) * 512 + s8 * 64;
  const double* wq = &wfld[(s8 >> 1) * 1026 + (s8 & 1) * 512];
  for (int dd = 0; dd < 16; ++dd) {
    f32x4 xv = *(const f32x4*)(xrow + dd * 4);
#pragma unroll
    for (int j = 0; j < 4; ++j) {
      double xd = (double)xv[j];
      const double* wrow = wq + (dd * 4 + j) * 8;
#pragma unroll
      for (int e = 0; e < 8; ++e) z[e] += xd * wrow[e];
    }
  }
#pragma unroll
  for (int e = 0; e < 8; ++e) {
    z[e] += __shfl_xor(z[e], 1);
    z[e] += __shfl_xor(z[e], 2);
    z[e] += __shfl_xor(z[e], 4);
  }
  if (s8 == 0) {
#pragma unroll
    for (int e = 0; e < 8; ++e) z[e] += bfv[e];
    int i1 = 0; double m1 = z[0];
#pragma unroll
    for (int e = 1; e < 8; ++e) if (z[e] > m1) { m1 = z[e]; i1 = e; }
    int i2 = -1; double m2 = -1e300;
#pragma unroll
    for (int e = 0; e < 8; ++e) if (e != i1 && z[e] > m2) { m2 = z[e]; i2 = e; }
    double s = exp(m2 - m1);
    int token = row0 + tok;
    g12[token] = make_float2((float)(1.0 / (1.0 + s)), (float)(s / (1.0 + s)));
    eidx[token] = (unsigned)(i1 | (i2 << 4));
  }
}

// ---------------- hist: per-block (256 tokens) expert histogram ----------------
__global__ __launch_bounds__(256) void k_hist(const unsigned int* __restrict__ eidx,
                                              unsigned int* __restrict__ bhist) {
  __shared__ unsigned int wcnt[4][8];
  const int tid = threadIdx.x;
  const int w = tid >> 6, lane = tid & 63;
  unsigned v = eidx[blockIdx.x * 256 + tid];
  int i1 = (int)(v & 15u), i2 = (int)((v >> 4) & 15u);
#pragma unroll
  for (int e = 0; e < 8; ++e) {
    unsigned long long m0 = __ballot(i1 == e);
    unsigned long long m1 = __ballot(i2 == e);
    if (lane == 0) wcnt[w][e] = (unsigned)(__popcll(m0) + __popcll(m1));
  }
  __syncthreads();
  if (tid < 8)
    bhist[blockIdx.x * 8 + tid] =
        wcnt[0][tid] + wcnt[1][tid] + wcnt[2][tid] + wcnt[3][tid];
}

// scan: wave e scans expert e's 512 block counts -> exclusive bases + meta
// meta[e]=64-row tile base, meta[8]=total tiles, meta[16+e]=count, meta[32+e]=row base
__global__ __launch_bounds__(512) void k_scan1(const unsigned int* __restrict__ bhist,
                                               unsigned int* __restrict__ bbase,
                                               unsigned int* __restrict__ meta) {
  __shared__ unsigned int tot[8];
  const int tid = threadIdx.x;
  const int e = tid >> 6, lane = tid & 63;
  unsigned run = 0;
  for (int c = 0; c < 8; ++c) {           // 8 chunks x 64 lanes = 512 blocks
    int b = c * 64 + lane;
    unsigned v = bhist[b * 8 + e];
    unsigned s = v;
#pragma unroll
    for (int d = 1; d < 64; d <<= 1) {
      unsigned t2 = __shfl_up(s, d);
      if (lane >= d) s += t2;
    }
    bbase[b * 8 + e] = run + s - v;       // exclusive within expert
    run += (unsigned)__shfl(s, 63);
  }
  if (lane == 63) tot[e] = run;
  __syncthreads();
  if (tid == 0) {
    unsigned bb = 0;
    for (int i = 0; i < 8; ++i) {
      meta[i] = bb;                 // 64-row tile base
      meta[16 + i] = tot[i];
      meta[32 + i] = bb * 64u;      // row base
      bb += (tot[i] + 63u) >> 6;
    }
    meta[8] = bb;
  }
}

// scatter: position = rowBase[e] + blockBase + waveBase + ballot rank. No atomics.
__global__ __launch_bounds__(256) void k_scatter2(const unsigned int* __restrict__ eidx,
                                                  const unsigned int* __restrict__ bbase,
                                                  const unsigned int* __restrict__ meta,
                                                  unsigned int* __restrict__ perm) {
  __shared__ unsigned int wcnt[4][8];
  const int tid = threadIdx.x;
  const int w = tid >> 6, lane = tid & 63;
  const int t = blockIdx.x * 256 + tid;
  unsigned v = eidx[t];
  int i1 = (int)(v & 15u), i2 = (int)((v >> 4) & 15u);
  unsigned long long m0[8], m1[8];
#pragma unroll
  for (int e = 0; e < 8; ++e) {
    m0[e] = __ballot(i1 == e);
    m1[e] = __ballot(i2 == e);
    if (lane == 0) wcnt[w][e] = (unsigned)(__popcll(m0[e]) + __popcll(m1[e]));
  }
  __syncthreads();
  const unsigned long long below = (1ull << lane) - 1ull;
#pragma unroll
  for (int e = 0; e < 8; ++e) {
    unsigned base = meta[32 + e] + bbase[blockIdx.x * 8 + e];
    for (int w2 = 0; w2 < w; ++w2) base += wcnt[w2][e];
    if (i1 == e) {
      unsigned r = (unsigned)__popcll(m0[e] & below);
      perm[base + r] = (unsigned)(t * 2);
    }
    if (i2 == e) {
      unsigned r = (unsigned)__popcll(m0[e]) + (unsigned)__popcll(m1[e] & below);
      perm[base + r] = (unsigned)(t * 2 + 1);
    }
  }
}

// ------------- grouped expert FFN (R6 config: M=64, single 34KB LDS) -------------
// e1=relu(h@W1+b1); eo=e1@W2+b2; proj=eo@Wh1
__global__ __launch_bounds__(512) void k_expert(const unsigned short* __restrict__ hbuf,
                                                const unsigned short* __restrict__ w1t,
                                                const unsigned short* __restrict__ w2t,
                                                const unsigned short* __restrict__ wh1t,
                                                const float* __restrict__ b1,
                                                const float* __restrict__ b2,
                                                const unsigned int* __restrict__ meta,
                                                const unsigned int* __restrict__ perm,
                                                unsigned short* __restrict__ proj) {
  __shared__ unsigned short xt[64 * 264];    // h -> e1 -> eo (single buffer)
  __shared__ int ptok[64];
  const int b = blockIdx.x;
  if (b >= (int)meta[8]) return;
  int e = 0;
  while (e < 7 && (int)meta[e + 1] <= b) ++e;
  const int limit = (int)(meta[e] * 64u + meta[16 + e]);  // first invalid row
  const int row0 = b * 64;
  const int tid = threadIdx.x;
  if (tid < 64) {
    int r = row0 + tid;
    ptok[tid] = (r < limit) ? (int)perm[r] : -1;
  }
  __syncthreads();
#pragma unroll
  for (int i = 0; i < 4; ++i) {
    int flat = tid + i * 512;
    int r = flat >> 5, c8 = flat & 31;
    int pt = ptok[r];
    s16x8 v = (s16x8)(short)0;
    if (pt >= 0) {
      int token = pt >> 1;
      v = *(const s16x8*)(hbuf + (size_t)token * 256 + c8 * 8);
    }
    *(s16x8*)&xt[r * 264 + c8 * 8] = v;
  }
  __syncthreads();

  const int lane = tid & 63, wid = tid >> 6;  // 8 waves: 64 rows x 32 cols each
  const int arow = lane & 15;
  const int koff = (lane >> 4) * 8;
  const int r4 = (lane >> 4) * 4;
  const int colb = wid * 32 + (lane & 15);

  f32x4 acc[4][2];
  // ---- G1: acc = h @ W1 ----
#pragma unroll
  for (int mi = 0; mi < 4; ++mi) { acc[mi][0] = (f32x4)0.0f; acc[mi][1] = (f32x4)0.0f; }
  const unsigned short* w1e = w1t + (size_t)e * 65536;
#pragma unroll
  for (int kk = 0; kk < 8; ++kk) {
    int k0 = kk * 32 + koff;
    s16x8 af[4], bfr[2];
#pragma unroll
    for (int mi = 0; mi < 4; ++mi)
      af[mi] = *(const s16x8*)&xt[(arow + mi * 16) * 264 + k0];
#pragma unroll
    for (int ni = 0; ni < 2; ++ni)
      bfr[ni] = *(const s16x8*)(w1e + (size_t)(colb + ni * 16) * 256 + k0);
#pragma unroll
    for (int mi = 0; mi < 4; ++mi)
#pragma unroll
      for (int ni = 0; ni < 2; ++ni)
        acc[mi][ni] = __builtin_amdgcn_mfma_f32_16x16x32_bf16(af[mi], bfr[ni], acc[mi][ni], 0, 0, 0);
  }
  __syncthreads();   // all waves done reading h from xt
#pragma unroll
  for (int ni = 0; ni < 2; ++ni) {
    int col = colb + ni * 16;
    float bb1 = b1[e * 256 + col];
#pragma unroll
    for (int mi = 0; mi < 4; ++mi) {
      int rl = mi * 16 + r4;
#pragma unroll
      for (int j = 0; j < 4; ++j) {
        float v = acc[mi][ni][j] + bb1;
        v = v > 0.f ? v : 0.f;
        xt[(rl + j) * 264 + col] = f2bf(v);      // e1 overwrites h
      }
    }
  }
  __syncthreads();

  // ---- G2: acc = e1 @ W2 ----
#pragma unroll
  for (int mi = 0; mi < 4; ++mi) { acc[mi][0] = (f32x4)0.0f; acc[mi][1] = (f32x4)0.0f; }
  const unsigned short* w2e = w2t + (size_t)e * 65536;
#pragma unroll
  for (int kk = 0; kk < 8; ++kk) {
    int k0 = kk * 32 + koff;
    s16x8 af[4], bfr[2];
#pragma unroll
    for (int mi = 0; mi < 4; ++mi)
      af[mi] = *(const s16x8*)&xt[(arow + mi * 16) * 264 + k0];
#pragma unroll
    for (int ni = 0; ni < 2; ++ni)
      bfr[ni] = *(const s16x8*)(w2e + (size_t)(colb + ni * 16) * 256 + k0);
#pragma unroll
    for (int mi = 0; mi < 4; ++mi)
#pragma unroll
      for (int ni = 0; ni < 2; ++ni)
        acc[mi][ni] = __builtin_amdgcn_mfma_f32_16x16x32_bf16(af[mi], bfr[ni], acc[mi][ni], 0, 0, 0);
  }
  __syncthreads();   // all waves done reading e1 from xt
#pragma unroll
  for (int ni = 0; ni < 2; ++ni) {
    int col = colb + ni * 16;
    float bb2 = b2[e * 256 + col];
#pragma unroll
    for (int mi = 0; mi < 4; ++mi) {
      int rl = mi * 16 + r4;
#pragma unroll
      for (int j = 0; j < 4; ++j)
        xt[(rl + j) * 264 + col] = f2bf(acc[mi][ni][j] + bb2);   // eo overwrites e1
    }
  }
  __syncthreads();

  // ---- G3: proj = eo @ Wh1  (output 64 x 128; 8 waves x 16 cols) ----
  f32x4 acc3[4];
#pragma unroll
  for (int mi = 0; mi < 4; ++mi) acc3[mi] = (f32x4)0.0f;
  const int col3 = wid * 16 + (lane & 15);
#pragma unroll
  for (int kk = 0; kk < 8; ++kk) {
    int k0 = kk * 32 + koff;
    s16x8 af[4];
#pragma unroll
    for (int mi = 0; mi < 4; ++mi)
      af[mi] = *(const s16x8*)&xt[(arow + mi * 16) * 264 + k0];
    s16x8 bfr = *(const s16x8*)(wh1t + (size_t)col3 * 256 + k0);
#pragma unroll
    for (int mi = 0; mi < 4; ++mi)
      acc3[mi] = __builtin_amdgcn_mfma_f32_16x16x32_bf16(af[mi], bfr, acc3[mi], 0, 0, 0);
  }
#pragma unroll
  for (int mi = 0; mi < 4; ++mi) {
#pragma unroll
    for (int j = 0; j < 4; ++j) {
      int rl = mi * 16 + r4 + j;
      int pt = ptok[rl];
      if (pt >= 0)
        proj[(size_t)pt * 128 + col3] = f2bf(acc3[mi][j]);
    }
  }
}

// ------------- combine + head: y=relu(g1*p1+g2*p2+bh1); out=y@Wh2+bh2 -------------
__global__ __launch_bounds__(256) void k_head(const unsigned short* __restrict__ proj,
                                              const float2* __restrict__ g12,
                                              const float* __restrict__ bh1,
                                              const float* __restrict__ wh2,
                                              const float* __restrict__ bh2,
                                              float* __restrict__ out) {
  __shared__ float sbh1[128];
  __shared__ float swh2[128];
  const int tid = threadIdx.x;
  if (tid < 128) { sbh1[tid] = bh1[tid]; swh2[tid] = wh2[tid]; }
  __syncthreads();
  const int token = blockIdx.x * 128 + (tid >> 1);
  const int half = tid & 1;
  const int j0 = half * 64;
  float2 g = g12[token];
  const unsigned short* p1 = proj + (size_t)token * 256 + j0;        // slot 0 row
  const unsigned short* p2 = p1 + 128;                               // slot 1 row
  float sum = 0.f;
#pragma unroll
  for (int c = 0; c < 8; ++c) {
    s16x8 a = *(const s16x8*)(p1 + c * 8);
    s16x8 b = *(const s16x8*)(p2 + c * 8);
#pragma unroll
    for (int jj = 0; jj < 8; ++jj) {
      int j = j0 + c * 8 + jj;
      float v = g.x * bf2f((unsigned short)a[jj]) + g.y * bf2f((unsigned short)b[jj]) + sbh1[j];
      v = fmaxf(v, 0.f);
      sum += v * swh2[j];
    }
  }
  sum += __shfl_xor(sum, 1);
  if (half == 0) out[token] = sum + bh2[0];
}

extern "C" void kernel_launch(void* const* d_in, const int* in_sizes, int n_in,
                              void* d_out, int out_size, void* d_ws, size_t ws_size,
                              hipStream_t stream) {
  const float* x   = (const float*)d_in[0];
  const float* Win = (const float*)d_in[1];
  const float* bin = (const float*)d_in[2];
  const float* W1  = (const float*)d_in[3];
  const float* b1  = (const float*)d_in[4];
  const float* W2  = (const float*)d_in[5];
  const float* b2  = (const float*)d_in[6];
  const float* Wg  = (const float*)d_in[7];
  const float* bg  = (const float*)d_in[8];
  const float* Wh1 = (const float*)d_in[9];
  const float* bh1 = (const float*)d_in[10];
  const float* Wh2 = (const float*)d_in[11];
  const float* bh2 = (const float*)d_in[12];

  char* ws = (char*)d_ws;
  size_t o = 0;
  auto alloc = [&](size_t n) { o = (o + 255) & ~(size_t)255; void* p = ws + o; o += n; return p; };
  unsigned short* wt_in = (unsigned short*)alloc(262144);
  unsigned short* w1t   = (unsigned short*)alloc(1048576);
  unsigned short* w2t   = (unsigned short*)alloc(1048576);
  unsigned short* wh1t  = (unsigned short*)alloc(65536);
  double*        wf     = (double*)alloc(32768);
  double*        bfv    = (double*)alloc(64);
  unsigned short* hbuf  = (unsigned short*)alloc((size_t)NB * 256 * 2);        // 67.1 MB
  float2*        g12    = (float2*)alloc((size_t)NB * 8);
  unsigned int*  eidx   = (unsigned int*)alloc((size_t)NB * 4);
  unsigned int*  bhist  = (unsigned int*)alloc(512 * 8 * 4);
  unsigned int*  bbase  = (unsigned int*)alloc(512 * 8 * 4);
  unsigned int*  meta   = (unsigned int*)alloc(256);
  unsigned int*  perm   = (unsigned int*)alloc(((size_t)NB * 2 + 2048) * 4);   // padded
  unsigned short* proj  = (unsigned short*)alloc((size_t)NB * 2 * 128 * 2);    // 67.1 MB
  (void)ws_size; (void)in_sizes; (void)n_in; (void)out_size;  // ~139.4 MB used

  k_prep_t<<<2048, 256, 0, stream>>>(Win, W1, W2, Wh1, wt_in, w1t, w2t, wh1t);
  k_prep_gate<<<16, 256, 0, stream>>>(Win, Wg, bin, bg, wf, bfv);
  k_hg<<<NB / 64, 512, 0, stream>>>(x, wt_in, bin, wf, bfv, hbuf, g12, eidx);
  k_hist<<<NB / 256, 256, 0, stream>>>(eidx, bhist);
  k_scan1<<<1, 512, 0, stream>>>(bhist, bbase, meta);
  k_scatter2<<<NB / 256, 256, 0, stream>>>(eidx, bbase, meta, perm);
  k_expert<<<NB * 2 / 64 + 8, 512, 0, stream>>>(hbuf, w1t, w2t, wh1t, b1, b2, meta, perm, proj);
  k_head<<<NB / 128, 256, 0, stream>>>(proj, g12, bh1, (const float*)Wh2, bh2, (float*)d_out);
}